// Round 1
// baseline (135.101 us; speedup 1.0000x reference)
//
#include <hip/hip_runtime.h>

typedef _Float16 h2 __attribute__((ext_vector_type(2)));
typedef unsigned int u32;

// Workspace layout (bytes); total 2 MB.
#define OFF_XP   0u         // half2[64][1024]  x, k-pairs packed, [kk][r]
#define OFF_YP   0x40000u   // half2[64][1024]  y
#define OFF_W1XP 0x80000u   // half2[64][256]   W1[:128] k-pair packed [kk][h]
#define OFF_W1YP 0x90000u   // half2[64][256]   W1[128:]
#define OFF_W2H  0xA0000u   // half2[128]       W2 h-pair packed
#define OFF_A2   0x100000u  // half2[128][1024] pre_x, [hh][j]
#define OFF_C2   0x180000u  // half2[128][1024] pre_y + b1, [hh][i]

__device__ __forceinline__ u32 pack2(float a, float b) {
  h2 v; v.x = (_Float16)a; v.y = (_Float16)b;
  return __builtin_bit_cast(u32, v);
}
__device__ __forceinline__ h2 as_h2(u32 u) { return __builtin_bit_cast(h2, u); }

__device__ __forceinline__ float fdot2(h2 a, h2 b, float c) {
#if __has_builtin(__builtin_amdgcn_fdot2)
  return __builtin_amdgcn_fdot2(a, b, c, false);
#else
  return (float)a.x * (float)b.x + (float)a.y * (float)b.y + c;
#endif
}
__device__ __forceinline__ h2 relu2(h2 t) {
  h2 z; z.x = (_Float16)0.0f; z.y = (_Float16)0.0f;
  return __builtin_elementwise_max(t, z);  // v_pk_max_f16
}

// K0: transpose/pack x,y -> [kk][r] half2; W1 -> k-pair packed [kk][h]; W2 -> h-pairs.
__global__ void k0_pack(const float* __restrict__ x, const float* __restrict__ y,
                        const float* __restrict__ W1, const float* __restrict__ W2,
                        u32* __restrict__ wsu) {
  const int b = blockIdx.x, tid = threadIdx.x;
  if (b < 128) {
    const float* src = (b < 64) ? x : y;
    u32* dst = wsu + ((b < 64) ? (OFF_XP >> 2) : (OFF_YP >> 2));
    const int bb = b & 63, kt = bb & 3, rt = bb >> 2;  // 32-k tile, 64-r tile
    __shared__ float sT[64][33];                        // +1 pad: conflict-free
    const int kl = tid & 31, rg = tid >> 5;
#pragma unroll
    for (int p = 0; p < 8; ++p) {
      const int r = p * 8 + rg;
      sT[r][kl] = src[(rt * 64 + r) * 128 + kt * 32 + kl];  // coalesced
    }
    __syncthreads();
    const int rl = tid & 63, kg = tid >> 6;
#pragma unroll
    for (int q = 0; q < 4; ++q) {
      const int kkl = q * 4 + kg;  // 0..15
      dst[(kt * 16 + kkl) * 1024 + rt * 64 + rl] =
          pack2(sT[rl][2 * kkl], sT[rl][2 * kkl + 1]);      // coalesced
    }
  } else if (b < 192) {
    const int kk = b - 128, h = tid;  // W1 rows are already h-contiguous
    wsu[(OFF_W1XP >> 2) + kk * 256 + h] =
        pack2(W1[(2 * kk) * 256 + h], W1[(2 * kk + 1) * 256 + h]);
    wsu[(OFF_W1YP >> 2) + kk * 256 + h] =
        pack2(W1[(128 + 2 * kk) * 256 + h], W1[(129 + 2 * kk) * 256 + h]);
  } else {
    if (tid < 128) wsu[(OFF_W2H >> 2) + tid] = pack2(W2[2 * tid], W2[2 * tid + 1]);
  }
}

// K1: pre_x = x@W1x -> a2[hh][j];  pre_y+b1 -> c2[hh][i].  fdot2 over 64 k-pairs.
__global__ __launch_bounds__(256) void k1_pre(u32* __restrict__ wsu,
                                              const float* __restrict__ b1) {
  const int b = blockIdx.x, tid = threadIdx.x;
  const int mat = b >> 7;            // 0: x->a2, 1: y->c2
  const int bb = b & 127, ht = bb & 3, rt = bb >> 2;  // 64-h tile, 32-r tile
  const int tx = tid & 15, ty = tid >> 4;
  const int r0 = rt * 32 + tx * 2;   // 2 rows/thread (lane-contiguous loads/stores)
  const int h0 = ht * 64 + ty * 4;   // 4 h/thread
  const u32* xp  = wsu + (mat ? (OFF_YP >> 2) : (OFF_XP >> 2));
  const u32* w1p = wsu + (mat ? (OFF_W1YP >> 2) : (OFF_W1XP >> 2));
  u32* dst = wsu + (mat ? (OFF_C2 >> 2) : (OFF_A2 >> 2));

  float acc[2][4];
#pragma unroll
  for (int r = 0; r < 2; ++r)
#pragma unroll
    for (int h = 0; h < 4; ++h) acc[r][h] = mat ? b1[h0 + h] : 0.0f;

  uint2 XV[4]; uint4 WV[4];          // depth-4 prefetch ring
#pragma unroll
  for (int s = 0; s < 4; ++s) {
    XV[s] = *(const uint2*)(xp + s * 1024 + r0);
    WV[s] = *(const uint4*)(w1p + s * 256 + h0);
  }
#pragma unroll 4
  for (int kk = 0; kk < 64; ++kk) {
    const int s = kk & 3;
    const uint2 xv = XV[s]; const uint4 wv = WV[s];
    const int nk = kk + 4;
    if (nk < 64) {
      XV[s] = *(const uint2*)(xp + nk * 1024 + r0);
      WV[s] = *(const uint4*)(w1p + nk * 256 + h0);
    }
    const u32 wa[4] = {wv.x, wv.y, wv.z, wv.w};
    const u32 xa[2] = {xv.x, xv.y};
#pragma unroll
    for (int r = 0; r < 2; ++r) {
      const h2 xr = as_h2(xa[r]);
#pragma unroll
      for (int h = 0; h < 4; ++h) acc[r][h] = fdot2(xr, as_h2(wa[h]), acc[r][h]);
    }
  }
  // store as h-pair packed [hh][r]; combine the 2 rows -> one 8B coalesced store
  const int hh0 = h0 >> 1;
  uint2 s0, s1;
  s0.x = pack2(acc[0][0], acc[0][1]); s0.y = pack2(acc[1][0], acc[1][1]);
  s1.x = pack2(acc[0][2], acc[0][3]); s1.y = pack2(acc[1][2], acc[1][3]);
  *(uint2*)(dst + hh0 * 1024 + r0) = s0;
  *(uint2*)(dst + (hh0 + 1) * 1024 + r0) = s1;
}

// K2: main N^2 kernel. 256 blocks of 64x64 pairs; 4x4 regs/thread; no LDS.
// d[i][j] = sum_h relu(a[j,h]+c[i,h])*w2[h] via pk_add/pk_max/dot2 on h-pairs.
__global__ __launch_bounds__(256) void k2_main(const u32* __restrict__ wsu,
                                               const float* __restrict__ B2,
                                               float* __restrict__ out) {
  const int bi = blockIdx.x >> 4, bj = blockIdx.x & 15;
  const int tid = threadIdx.x;
  const int tx = tid & 15, ty = tid >> 4;
  const int i0 = bi * 64 + ty * 4, j0 = bj * 64 + tx * 4;
  const uint4* pa = (const uint4*)(wsu + (OFF_A2 >> 2) + j0);  // +hh*256 (uint4)
  const uint4* pc = (const uint4*)(wsu + (OFF_C2 >> 2) + i0);
  const u32* pw = wsu + (OFF_W2H >> 2);

  float acc[16];
#pragma unroll
  for (int p = 0; p < 16; ++p) acc[p] = 0.0f;

  uint4 A[4], C[4]; u32 WR[4];       // depth-4 prefetch ring (~300 cyc cover)
#pragma unroll
  for (int s = 0; s < 4; ++s) { A[s] = pa[s * 256]; C[s] = pc[s * 256]; WR[s] = pw[s]; }

#pragma unroll 4
  for (int hh = 0; hh < 128; ++hh) {
    const int s = hh & 3;
    const uint4 av = A[s], cv = C[s];
    const h2 w = as_h2(WR[s]);
    const int nh = hh + 4;
    if (nh < 128) { A[s] = pa[nh * 256]; C[s] = pc[nh * 256]; WR[s] = pw[nh]; }
    const u32 aa[4] = {av.x, av.y, av.z, av.w};
    const u32 ca[4] = {cv.x, cv.y, cv.z, cv.w};
#pragma unroll
    for (int ii = 0; ii < 4; ++ii) {
      const h2 ci = as_h2(ca[ii]);
#pragma unroll
      for (int jj = 0; jj < 4; ++jj) {
        h2 t = as_h2(aa[jj]) + ci;   // v_pk_add_f16
        t = relu2(t);                // v_pk_max_f16
        acc[ii * 4 + jj] = fdot2(t, w, acc[ii * 4 + jj]);  // v_dot2_f32_f16
      }
    }
  }

  // result = (1/n) sum_i (d_ii + b2)  -  (1/n^2) sum_ij exp(d_ij + b2 - 1)
  const float b2 = B2[0];
  float sm = 0.0f;
#pragma unroll
  for (int p = 0; p < 16; ++p) sm += __expf(acc[p] + (b2 - 1.0f));
#pragma unroll
  for (int off = 32; off > 0; off >>= 1) sm += __shfl_down(sm, off, 64);
  if ((tid & 63) == 0) atomicAdd(out, sm * (-1.0f / 1048576.0f));
  if (bi == bj && tx == ty) {        // this thread's tile holds global diagonal elems
    float d = 0.0f;
#pragma unroll
    for (int a = 0; a < 4; ++a) d += acc[a * 5] + b2;
    atomicAdd(out, d * (1.0f / 1024.0f));
  }
}

extern "C" void kernel_launch(void* const* d_in, const int* in_sizes, int n_in,
                              void* d_out, int out_size, void* d_ws, size_t ws_size,
                              hipStream_t stream) {
  const float* x  = (const float*)d_in[0];
  const float* y  = (const float*)d_in[1];
  const float* W1 = (const float*)d_in[2];
  const float* b1 = (const float*)d_in[3];
  const float* W2 = (const float*)d_in[4];
  const float* b2 = (const float*)d_in[5];
  u32* wsu = (u32*)d_ws;

  hipMemsetAsync(d_out, 0, sizeof(float), stream);  // atomic accumulator
  hipLaunchKernelGGL(k0_pack, dim3(193), dim3(256), 0, stream, x, y, W1, W2, wsu);
  hipLaunchKernelGGL(k1_pre, dim3(256), dim3(256), 0, stream, wsu, b1);
  hipLaunchKernelGGL(k2_main, dim3(256), dim3(256), 0, stream, wsu, b2, (float*)d_out);
}

// Round 2
// 107.697 us; speedup vs baseline: 1.2545x; 1.2545x over previous
//
#include <hip/hip_runtime.h>

typedef _Float16 h2 __attribute__((ext_vector_type(2)));
typedef unsigned int u32;

// Workspace layout (bytes); total 2 MB.
#define OFF_XP   0u         // half2[64][1024]   x, k-pairs packed, [kk][r]
#define OFF_YP   0x40000u   // half2[64][1024]   y
#define OFF_W1XP 0x80000u   // half2[64][256]    W1[:128] k-pair packed [kk][h]
#define OFF_W1YP 0x90000u   // half2[64][256]    W1[128:]
#define OFF_W2H  0xA0000u   // half2[128]        W2 h-pair packed
#define OFF_A2   0x100000u  // half2, TILED: [32 rtile][128 hh][32 rpair-in-tile]... see k1
#define OFF_C2   0x180000u  // same tiling for pre_y + b1

__device__ __forceinline__ u32 pack2(float a, float b) {
  h2 v; v.x = (_Float16)a; v.y = (_Float16)b;
  return __builtin_bit_cast(u32, v);
}
__device__ __forceinline__ h2 as_h2(u32 u) { return __builtin_bit_cast(h2, u); }

__device__ __forceinline__ float fdot2(h2 a, h2 b, float c) {
#if __has_builtin(__builtin_amdgcn_fdot2)
  return __builtin_amdgcn_fdot2(a, b, c, false);
#else
  return (float)a.x * (float)b.x + (float)a.y * (float)b.y + c;
#endif
}
__device__ __forceinline__ h2 relu2(h2 t) {
  h2 z; z.x = (_Float16)0.0f; z.y = (_Float16)0.0f;
  return __builtin_elementwise_max(t, z);  // v_pk_max_f16
}

// K0: transpose/pack x,y -> [kk][r] half2; W1 -> k-pair packed [kk][h]; W2 -> h-pairs.
__global__ void k0_pack(const float* __restrict__ x, const float* __restrict__ y,
                        const float* __restrict__ W1, const float* __restrict__ W2,
                        u32* __restrict__ wsu) {
  const int b = blockIdx.x, tid = threadIdx.x;
  if (b < 128) {
    const float* src = (b < 64) ? x : y;
    u32* dst = wsu + ((b < 64) ? (OFF_XP >> 2) : (OFF_YP >> 2));
    const int bb = b & 63, kt = bb & 3, rt = bb >> 2;  // 32-k tile, 64-r tile
    __shared__ float sT[64][33];                        // +1 pad: conflict-free
    const int kl = tid & 31, rg = tid >> 5;
#pragma unroll
    for (int p = 0; p < 8; ++p) {
      const int r = p * 8 + rg;
      sT[r][kl] = src[(rt * 64 + r) * 128 + kt * 32 + kl];  // coalesced
    }
    __syncthreads();
    const int rl = tid & 63, kg = tid >> 6;
#pragma unroll
    for (int q = 0; q < 4; ++q) {
      const int kkl = q * 4 + kg;  // 0..15
      dst[(kt * 16 + kkl) * 1024 + rt * 64 + rl] =
          pack2(sT[rl][2 * kkl], sT[rl][2 * kkl + 1]);      // coalesced
    }
  } else if (b < 192) {
    const int kk = b - 128, h = tid;  // W1 rows are already h-contiguous
    wsu[(OFF_W1XP >> 2) + kk * 256 + h] =
        pack2(W1[(2 * kk) * 256 + h], W1[(2 * kk + 1) * 256 + h]);
    wsu[(OFF_W1YP >> 2) + kk * 256 + h] =
        pack2(W1[(128 + 2 * kk) * 256 + h], W1[(129 + 2 * kk) * 256 + h]);
  } else {
    if (tid < 128) wsu[(OFF_W2H >> 2) + tid] = pack2(W2[2 * tid], W2[2 * tid + 1]);
  }
}

// K1: pre_x -> a2t, pre_y + b1 -> c2t.  512 blocks (2 waves/SIMD), depth-8 ring.
// Output tiled layout (u32 = half2 of h-pair): idx = rt*4096 + hh*32 + (r&31).
__global__ __launch_bounds__(256) void k1_pre(u32* __restrict__ wsu,
                                              const float* __restrict__ b1) {
  const int b = blockIdx.x, tid = threadIdx.x;
  const int mat = b >> 8;                       // 0: x->a2t, 1: y->c2t
  const int bb = b & 255, ht = bb & 7, rt = bb >> 3;  // 32-h tile, 32-r tile
  const int tx = tid & 31, ty = tid >> 5;       // r lane, h group
  const int h0 = ht * 32 + ty * 4;              // 4 h / thread, 1 r / thread
  const u32* xp  = wsu + (mat ? (OFF_YP >> 2) : (OFF_XP >> 2)) + rt * 32 + tx;
  const u32* w1p = wsu + (mat ? (OFF_W1YP >> 2) : (OFF_W1XP >> 2)) + h0;
  u32* dst = wsu + (mat ? (OFF_C2 >> 2) : (OFF_A2 >> 2)) + rt * 4096 + tx;

  float acc[4];
  if (mat) {
    const float4 bv = *(const float4*)(b1 + h0);
    acc[0] = bv.x; acc[1] = bv.y; acc[2] = bv.z; acc[3] = bv.w;
  } else {
    acc[0] = acc[1] = acc[2] = acc[3] = 0.0f;
  }

  u32 XR[8]; uint4 WR[8];                       // depth-8 prefetch ring
#pragma unroll
  for (int s = 0; s < 8; ++s) {
    XR[s] = xp[s * 1024];
    WR[s] = *(const uint4*)(w1p + s * 256);
  }
#pragma unroll 8
  for (int kk = 0; kk < 56; ++kk) {             // main: consume + prefetch kk+8
    const int s = kk & 7;
    const h2 xr = as_h2(XR[s]); const uint4 wv = WR[s];
    XR[s] = xp[(kk + 8) * 1024];
    WR[s] = *(const uint4*)(w1p + (kk + 8) * 256);
    acc[0] = fdot2(xr, as_h2(wv.x), acc[0]);
    acc[1] = fdot2(xr, as_h2(wv.y), acc[1]);
    acc[2] = fdot2(xr, as_h2(wv.z), acc[2]);
    acc[3] = fdot2(xr, as_h2(wv.w), acc[3]);
  }
#pragma unroll
  for (int kk = 56; kk < 64; ++kk) {            // tail: consume only
    const int s = kk & 7;
    const h2 xr = as_h2(XR[s]); const uint4 wv = WR[s];
    acc[0] = fdot2(xr, as_h2(wv.x), acc[0]);
    acc[1] = fdot2(xr, as_h2(wv.y), acc[1]);
    acc[2] = fdot2(xr, as_h2(wv.z), acc[2]);
    acc[3] = fdot2(xr, as_h2(wv.w), acc[3]);
  }
  const int hh0 = h0 >> 1;
  dst[hh0 * 32]       = pack2(acc[0], acc[1]);  // coalesced 128B per 32 lanes
  dst[(hh0 + 1) * 32] = pack2(acc[2], acc[3]);
}

// K2: main N^2 kernel. 1024 blocks of 32x32 pairs (4 waves/SIMD); 2x2 regs/thread.
// Operands are contiguous 16KB slabs; depth-8 ring; W2 from LDS broadcast.
__global__ __launch_bounds__(256) void k2_main(const u32* __restrict__ wsu,
                                               const float* __restrict__ B2,
                                               float* __restrict__ out) {
  const int bi = blockIdx.x >> 5, bj = blockIdx.x & 31;
  const int tid = threadIdx.x;
  const int tx = tid & 15, ty = tid >> 4;       // j-pair, i-pair
  const u32* pa = wsu + (OFF_A2 >> 2) + bj * 4096 + tx * 2;
  const u32* pc = wsu + (OFF_C2 >> 2) + bi * 4096 + ty * 2;

  __shared__ u32 sw[128];
  __shared__ float sred[4];
  if (tid < 128) sw[tid] = wsu[(OFF_W2H >> 2) + tid];
  __syncthreads();

  float acc[4] = {0.0f, 0.0f, 0.0f, 0.0f};
  uint2 A[8], C[8]; u32 W[8];                   // depth-8 prefetch ring
#pragma unroll
  for (int s = 0; s < 8; ++s) {
    A[s] = *(const uint2*)(pa + s * 32);
    C[s] = *(const uint2*)(pc + s * 32);
    W[s] = sw[s];
  }
#pragma unroll 8
  for (int hh = 0; hh < 120; ++hh) {            // main: consume + prefetch hh+8
    const int s = hh & 7;
    const uint2 av = A[s], cv = C[s];
    const h2 w = as_h2(W[s]);
    A[s] = *(const uint2*)(pa + (hh + 8) * 32);
    C[s] = *(const uint2*)(pc + (hh + 8) * 32);
    W[s] = sw[hh + 8];
    const h2 a0 = as_h2(av.x), a1 = as_h2(av.y);
    const h2 c0 = as_h2(cv.x), c1 = as_h2(cv.y);
    acc[0] = fdot2(relu2(a0 + c0), w, acc[0]);
    acc[1] = fdot2(relu2(a1 + c0), w, acc[1]);
    acc[2] = fdot2(relu2(a0 + c1), w, acc[2]);
    acc[3] = fdot2(relu2(a1 + c1), w, acc[3]);
  }
#pragma unroll
  for (int hh = 120; hh < 128; ++hh) {          // tail: consume only
    const int s = hh & 7;
    const uint2 av = A[s], cv = C[s];
    const h2 w = as_h2(W[s]);
    const h2 a0 = as_h2(av.x), a1 = as_h2(av.y);
    const h2 c0 = as_h2(cv.x), c1 = as_h2(cv.y);
    acc[0] = fdot2(relu2(a0 + c0), w, acc[0]);
    acc[1] = fdot2(relu2(a1 + c0), w, acc[1]);
    acc[2] = fdot2(relu2(a0 + c1), w, acc[2]);
    acc[3] = fdot2(relu2(a1 + c1), w, acc[3]);
  }

  // result = (1/n) sum_i (T1_ii + 1)  -  (1/n^2) sum_ij exp(T1_ij),
  // with T1_ij = d_ij + b2 - 1.  acc[] holds d_ij.
  const float b2 = B2[0];
  float val = 0.0f;
#pragma unroll
  for (int p = 0; p < 4; ++p) val += __expf(acc[p] + (b2 - 1.0f));
  val *= -1.0f / 1048576.0f;
  if (bi == bj && tx == ty)                     // diag elems: acc[0] and acc[3]
    val += (acc[0] + acc[3] + 2.0f * b2) * (1.0f / 1024.0f);
#pragma unroll
  for (int off = 32; off > 0; off >>= 1) val += __shfl_down(val, off, 64);
  if ((tid & 63) == 0) sred[tid >> 6] = val;
  __syncthreads();
  if (tid == 0) atomicAdd(out, sred[0] + sred[1] + sred[2] + sred[3]);
}

extern "C" void kernel_launch(void* const* d_in, const int* in_sizes, int n_in,
                              void* d_out, int out_size, void* d_ws, size_t ws_size,
                              hipStream_t stream) {
  const float* x  = (const float*)d_in[0];
  const float* y  = (const float*)d_in[1];
  const float* W1 = (const float*)d_in[2];
  const float* b1 = (const float*)d_in[3];
  const float* W2 = (const float*)d_in[4];
  const float* b2 = (const float*)d_in[5];
  u32* wsu = (u32*)d_ws;

  hipMemsetAsync(d_out, 0, sizeof(float), stream);  // atomic accumulator
  hipLaunchKernelGGL(k0_pack, dim3(193), dim3(256), 0, stream, x, y, W1, W2, wsu);
  hipLaunchKernelGGL(k1_pre, dim3(512), dim3(256), 0, stream, wsu, b1);
  hipLaunchKernelGGL(k2_main, dim3(1024), dim3(256), 0, stream, wsu, b2, (float*)d_out);
}

// Round 3
// 91.525 us; speedup vs baseline: 1.4761x; 1.1767x over previous
//
#include <hip/hip_runtime.h>

typedef _Float16 h2 __attribute__((ext_vector_type(2)));
typedef unsigned int u32;

// Workspace layout (bytes); total 2 MB.
#define OFF_XP   0u         // half2[64][1024]   x, k-pairs packed, [kk][r]
#define OFF_YP   0x40000u   // half2[64][1024]   y
#define OFF_W1XP 0x80000u   // half2[64][256]    W1[:128] k-pair packed [kk][h]
#define OFF_W1YP 0x90000u   // half2[64][256]    W1[128:]
#define OFF_A2   0x100000u  // half2 TILED: [32 slab][32 row][128 hh]  (pre_x)
#define OFF_C2   0x180000u  // same tiling      (pre_y + b1)

__device__ __forceinline__ u32 pack2(float a, float b) {
  h2 v; v.x = (_Float16)a; v.y = (_Float16)b;
  return __builtin_bit_cast(u32, v);
}
__device__ __forceinline__ h2 as_h2(u32 u) { return __builtin_bit_cast(h2, u); }

__device__ __forceinline__ float fdot2(h2 a, h2 b, float c) {
#if __has_builtin(__builtin_amdgcn_fdot2)
  return __builtin_amdgcn_fdot2(a, b, c, false);
#else
  return (float)a.x * (float)b.x + (float)a.y * (float)b.y + c;
#endif
}
__device__ __forceinline__ h2 relu2(h2 t) {
  h2 z; z.x = (_Float16)0.0f; z.y = (_Float16)0.0f;
  return __builtin_elementwise_max(t, z);  // v_pk_max_f16
}

// K0: transpose/pack x,y -> [kk][r] half2; W1 -> k-pair packed [kk][h]. Zeroes out.
__global__ void k0_pack(const float* __restrict__ x, const float* __restrict__ y,
                        const float* __restrict__ W1, u32* __restrict__ wsu,
                        float* __restrict__ out) {
  const int b = blockIdx.x, tid = threadIdx.x;
  if (b == 0 && tid == 0) out[0] = 0.0f;  // atomic accumulator init (d_out is poisoned)
  if (b < 128) {
    const float* src = (b < 64) ? x : y;
    u32* dst = wsu + ((b < 64) ? (OFF_XP >> 2) : (OFF_YP >> 2));
    const int bb = b & 63, kt = bb & 3, rt = bb >> 2;  // 32-k tile, 64-r tile
    __shared__ float sT[64][33];                        // +1 pad: conflict-free
    const int kl = tid & 31, rg = tid >> 5;
#pragma unroll
    for (int p = 0; p < 8; ++p) {
      const int r = p * 8 + rg;
      sT[r][kl] = src[(rt * 64 + r) * 128 + kt * 32 + kl];  // coalesced
    }
    __syncthreads();
    const int rl = tid & 63, kg = tid >> 6;
#pragma unroll
    for (int q = 0; q < 4; ++q) {
      const int kkl = q * 4 + kg;  // 0..15
      dst[(kt * 16 + kkl) * 1024 + rt * 64 + rl] =
          pack2(sT[rl][2 * kkl], sT[rl][2 * kkl + 1]);      // coalesced
    }
  } else {
    const int kk = b - 128, h = tid;  // W1 rows are already h-contiguous
    wsu[(OFF_W1XP >> 2) + kk * 256 + h] =
        pack2(W1[(2 * kk) * 256 + h], W1[(2 * kk + 1) * 256 + h]);
    wsu[(OFF_W1YP >> 2) + kk * 256 + h] =
        pack2(W1[(128 + 2 * kk) * 256 + h], W1[(129 + 2 * kk) * 256 + h]);
  }
}

// K1: pre_x -> a2t, pre_y + b1 -> c2t.  512 blocks (2 waves/SIMD), depth-8 ring.
// Output layout (u32 = half2 h-pair): idx = rt*4096 + r*128 + hh.
__global__ __launch_bounds__(256) void k1_pre(u32* __restrict__ wsu,
                                              const float* __restrict__ b1) {
  const int b = blockIdx.x, tid = threadIdx.x;
  const int mat = b >> 8;                       // 0: x->a2t, 1: y->c2t
  const int bb = b & 255, ht = bb & 7, rt = bb >> 3;  // 32-h tile, 32-r tile
  const int tx = tid & 31, ty = tid >> 5;       // r lane, h group
  const int h0 = ht * 32 + ty * 4;              // 4 h / thread, 1 r / thread
  const u32* xp  = wsu + (mat ? (OFF_YP >> 2) : (OFF_XP >> 2)) + rt * 32 + tx;
  const u32* w1p = wsu + (mat ? (OFF_W1YP >> 2) : (OFF_W1XP >> 2)) + h0;
  u32* dst = wsu + (mat ? (OFF_C2 >> 2) : (OFF_A2 >> 2)) + rt * 4096 + tx * 128;

  float acc[4];
  if (mat) {
    const float4 bv = *(const float4*)(b1 + h0);
    acc[0] = bv.x; acc[1] = bv.y; acc[2] = bv.z; acc[3] = bv.w;
  } else {
    acc[0] = acc[1] = acc[2] = acc[3] = 0.0f;
  }

  u32 XR[8]; uint4 WR[8];                       // depth-8 prefetch ring
#pragma unroll
  for (int s = 0; s < 8; ++s) {
    XR[s] = xp[s * 1024];
    WR[s] = *(const uint4*)(w1p + s * 256);
  }
#pragma unroll 8
  for (int kk = 0; kk < 56; ++kk) {             // main: consume + prefetch kk+8
    const int s = kk & 7;
    const h2 xr = as_h2(XR[s]); const uint4 wv = WR[s];
    XR[s] = xp[(kk + 8) * 1024];
    WR[s] = *(const uint4*)(w1p + (kk + 8) * 256);
    acc[0] = fdot2(xr, as_h2(wv.x), acc[0]);
    acc[1] = fdot2(xr, as_h2(wv.y), acc[1]);
    acc[2] = fdot2(xr, as_h2(wv.z), acc[2]);
    acc[3] = fdot2(xr, as_h2(wv.w), acc[3]);
  }
#pragma unroll
  for (int kk = 56; kk < 64; ++kk) {            // tail: consume only
    const int s = kk & 7;
    const h2 xr = as_h2(XR[s]); const uint4 wv = WR[s];
    acc[0] = fdot2(xr, as_h2(wv.x), acc[0]);
    acc[1] = fdot2(xr, as_h2(wv.y), acc[1]);
    acc[2] = fdot2(xr, as_h2(wv.z), acc[2]);
    acc[3] = fdot2(xr, as_h2(wv.w), acc[3]);
  }
  const int hh0 = ht * 16 + ty * 2;             // even -> 8B-aligned uint2 store
  uint2 sv;
  sv.x = pack2(acc[0], acc[1]);
  sv.y = pack2(acc[2], acc[3]);
  *(uint2*)(dst + hh0) = sv;
}

// K2: main N^2 kernel. 1024 blocks of 32x32 pairs (4 waves/SIMD); 2x2/thread.
// Block stages its 16KB A-slab + 16KB C-slab into LDS once (kills the 16x
// redundant L2 reads that bound R2), then ds_read_b128 (4 hh/instr) with
// XOR-swizzled uint4 rows (max 2-way aliasing = free per m136).
__global__ __launch_bounds__(256) void k2_main(const u32* __restrict__ wsu,
                                               const float* __restrict__ W2g,
                                               const float* __restrict__ B2,
                                               float* __restrict__ out) {
  const int bi = blockIdx.x >> 5, bj = blockIdx.x & 31;
  const int tid = threadIdx.x;
  const int tx = tid & 15, ty = tid >> 4;       // jpair, ipair

  __shared__ uint4 sA4[32 * 32];                // [row][quad^swz]
  __shared__ uint4 sC4[32 * 32];
  __shared__ uint4 sW4[32];
  __shared__ float sred[4];
  u32* sW2 = (u32*)sW4;

  {                                             // stage slabs (once)
    const u32* gA = wsu + (OFF_A2 >> 2) + bj * 4096;
    const u32* gC = wsu + (OFF_C2 >> 2) + bi * 4096;
    const int j = tid >> 3, q8 = tid & 7, sw = (j >> 1) & 7;
#pragma unroll
    for (int m = 0; m < 4; ++m) {
      const int q = q8 + 8 * m;
      sA4[j * 32 + (q ^ sw)] = *(const uint4*)(gA + j * 128 + q * 4);
      sC4[j * 32 + (q ^ sw)] = *(const uint4*)(gC + j * 128 + q * 4);
    }
    if (tid < 128) sW2[tid] = pack2(W2g[2 * tid], W2g[2 * tid + 1]);
  }
  __syncthreads();

  const uint4* rA0 = sA4 + (2 * tx) * 32;       // rows 2tx, 2tx+1
  const uint4* rA1 = rA0 + 32;
  const uint4* rC0 = sC4 + (2 * ty) * 32;       // rows 2ty, 2ty+1
  const uint4* rC1 = rC0 + 32;
  const int swzA = tx & 7, swzC = ty & 7;

  float acc[4] = {0.0f, 0.0f, 0.0f, 0.0f};
#pragma unroll 4
  for (int g = 0; g < 32; ++g) {                // 4 hh per step
    const uint4 av0 = rA0[g ^ swzA], av1 = rA1[g ^ swzA];
    const uint4 cv0 = rC0[g ^ swzC], cv1 = rC1[g ^ swzC];
    const uint4 wv = sW4[g];
    const u32 a0[4] = {av0.x, av0.y, av0.z, av0.w};
    const u32 a1[4] = {av1.x, av1.y, av1.z, av1.w};
    const u32 c0[4] = {cv0.x, cv0.y, cv0.z, cv0.w};
    const u32 c1[4] = {cv1.x, cv1.y, cv1.z, cv1.w};
    const u32 ww[4] = {wv.x, wv.y, wv.z, wv.w};
#pragma unroll
    for (int m = 0; m < 4; ++m) {
      const h2 A0 = as_h2(a0[m]), A1 = as_h2(a1[m]);
      const h2 C0 = as_h2(c0[m]), C1 = as_h2(c1[m]);
      const h2 w = as_h2(ww[m]);
      acc[0] = fdot2(relu2(A0 + C0), w, acc[0]);
      acc[1] = fdot2(relu2(A1 + C0), w, acc[1]);
      acc[2] = fdot2(relu2(A0 + C1), w, acc[2]);
      acc[3] = fdot2(relu2(A1 + C1), w, acc[3]);
    }
  }

  // result = (1/n) sum_i (T1_ii + 1) - (1/n^2) sum_ij exp(T1_ij),
  // T1_ij = d_ij + b2 - 1.  acc[] holds d_ij.
  const float b2 = B2[0];
  float val = 0.0f;
#pragma unroll
  for (int p = 0; p < 4; ++p) val += __expf(acc[p] + (b2 - 1.0f));
  val *= -1.0f / 1048576.0f;
  if (bi == bj && tx == ty)                     // diag elems: acc[0], acc[3]
    val += (acc[0] + acc[3] + 2.0f * b2) * (1.0f / 1024.0f);
#pragma unroll
  for (int off = 32; off > 0; off >>= 1) val += __shfl_down(val, off, 64);
  if ((tid & 63) == 0) sred[tid >> 6] = val;
  __syncthreads();
  if (tid == 0) atomicAdd(out, sred[0] + sred[1] + sred[2] + sred[3]);
}

extern "C" void kernel_launch(void* const* d_in, const int* in_sizes, int n_in,
                              void* d_out, int out_size, void* d_ws, size_t ws_size,
                              hipStream_t stream) {
  const float* x  = (const float*)d_in[0];
  const float* y  = (const float*)d_in[1];
  const float* W1 = (const float*)d_in[2];
  const float* b1 = (const float*)d_in[3];
  const float* W2 = (const float*)d_in[4];
  const float* b2 = (const float*)d_in[5];
  u32* wsu = (u32*)d_ws;

  hipLaunchKernelGGL(k0_pack, dim3(192), dim3(256), 0, stream, x, y, W1, wsu,
                     (float*)d_out);
  hipLaunchKernelGGL(k1_pre, dim3(512), dim3(256), 0, stream, wsu, b1);
  hipLaunchKernelGGL(k2_main, dim3(1024), dim3(256), 0, stream, wsu, W2, b2,
                     (float*)d_out);
}